// Round 1
// baseline (610.208 us; speedup 1.0000x reference)
//
#include <hip/hip_runtime.h>
#include <stdint.h>

// Problem constants (reference: T,B,I,H,K = 200,2048,128,128,4)
#define T_DIM 200
#define B_DIM 2048
#define I_DIM 128
#define H_DIM 128
#define NTILE 4   // ceil(T/64) t-tiles in K1

typedef float  f32x4  __attribute__((ext_vector_type(4)));
typedef __bf16 bf16x8 __attribute__((ext_vector_type(8)));

union BF8 {
    ushort4        u2[2];
    unsigned short us[8];
    bf16x8         v;
};

static __device__ __forceinline__ unsigned short f2bf(float f) {
    union { float f; unsigned u; } c; c.f = f;
    unsigned u = c.u + (0x7FFFu + ((c.u >> 16) & 1u));   // RNE
    return (unsigned short)(u >> 16);
}
static __device__ __forceinline__ float bf2f(unsigned short s) {
    union { unsigned u; float f; } c; c.u = ((unsigned)s) << 16;
    return c.f;
}

// ---------------------------------------------------------------------------
// K1: x1[t,b,:] = x[t,b,:] @ w1^T + b1 for t < L[b], bf16 MFMA 16x16x32.
// Output layout TRANSPOSED: x1w[b][h][t] (bf16) so K3 can read h-major rows.
// Also emits partial[b][tile][i] = sum over valid t in this 64-tile of x[t,b,i].
// grid = (NTILE, B), block = 256 (4 waves; wave w owns h in [32w, 32w+32)).
// ---------------------------------------------------------------------------
__global__ __launch_bounds__(256) void k1_gemm(
    const float* __restrict__ x, const int* __restrict__ lengths,
    const float* __restrict__ w1, const float* __restrict__ b1,
    unsigned short* __restrict__ x1w, float* __restrict__ partial)
{
    const int b    = blockIdx.y;
    const int tile = blockIdx.x;
    const int L    = lengths[b];
    const int t0   = tile * 64;
    if (t0 >= L) return;                       // tiles past L never read downstream
    const int tend  = (L < t0 + 64) ? L : (t0 + 64);
    const int nrows = tend - t0;               // 1..64 valid rows

    // A-tile staging, padded +8 bf16 (16B) to break ds_read_b128 conflicts
    __shared__ __align__(16) unsigned short xs[64][136];

    const int tid = threadIdx.x;

    // stage 64x128 fp32 rows -> bf16 LDS (rows >= nrows left garbage; masked later)
    for (int it = tid; it < 64 * 32; it += 256) {
        const int r = it >> 5, f4 = it & 31;
        if (r < nrows) {
            const float4 v = *(const float4*)(x + ((size_t)(t0 + r) * B_DIM + b) * I_DIM + f4 * 4);
            *(ushort4*)(&xs[r][f4 * 4]) =
                make_ushort4(f2bf(v.x), f2bf(v.y), f2bf(v.z), f2bf(v.w));
        }
    }
    __syncthreads();

    // per-tile column sums (for K2 prefix sums); bf16-sourced is within budget
    if (tid < 128) {
        float s = 0.f;
        for (int r = 0; r < nrows; ++r) s += bf2f(xs[r][tid]);
        partial[((size_t)b * NTILE + tile) * I_DIM + tid] = s;
    }

    const int lane = tid & 63;
    const int wv   = tid >> 6;     // wave 0..3
    const int l15  = lane & 15;
    const int quad = lane >> 4;

    // B fragments: B[k][n] = w1[n][k] -> 8 consecutive floats of w1 row n.
    bf16x8 bfr[2][4];
    #pragma unroll
    for (int nt = 0; nt < 2; ++nt) {
        const int n = wv * 32 + nt * 16 + l15;
        #pragma unroll
        for (int ks = 0; ks < 4; ++ks) {
            const int kc = ks * 32 + quad * 8;
            const float4 p0 = *(const float4*)(w1 + (size_t)n * I_DIM + kc);
            const float4 p1 = *(const float4*)(w1 + (size_t)n * I_DIM + kc + 4);
            BF8 t;
            t.u2[0] = make_ushort4(f2bf(p0.x), f2bf(p0.y), f2bf(p0.z), f2bf(p0.w));
            t.u2[1] = make_ushort4(f2bf(p1.x), f2bf(p1.y), f2bf(p1.z), f2bf(p1.w));
            bfr[nt][ks] = t.v;
        }
    }

    f32x4 acc[4][2];
    #pragma unroll
    for (int mt = 0; mt < 4; ++mt)
        #pragma unroll
        for (int nt = 0; nt < 2; ++nt)
            acc[mt][nt] = (f32x4){0.f, 0.f, 0.f, 0.f};

    #pragma unroll
    for (int mt = 0; mt < 4; ++mt) {
        bf16x8 afr[4];
        #pragma unroll
        for (int ks = 0; ks < 4; ++ks)
            afr[ks] = *(const bf16x8*)&xs[mt * 16 + l15][ks * 32 + quad * 8];
        #pragma unroll
        for (int nt = 0; nt < 2; ++nt)
            #pragma unroll
            for (int ks = 0; ks < 4; ++ks)
                acc[mt][nt] = __builtin_amdgcn_mfma_f32_16x16x32_bf16(
                    afr[ks], bfr[nt][ks], acc[mt][nt], 0, 0, 0);
    }

    // epilogue: +bias, cvt bf16, store transposed x1w[b][h][t] (4 consecutive t / lane)
    #pragma unroll
    for (int nt = 0; nt < 2; ++nt) {
        const int h = wv * 32 + nt * 16 + l15;
        const float bias = b1[h];
        unsigned short* orow = x1w + (size_t)(b * H_DIM + h) * T_DIM;
        #pragma unroll
        for (int mt = 0; mt < 4; ++mt) {
            const int tb = t0 + mt * 16 + quad * 4;
            if (tb >= tend) continue;
            unsigned short q[4];
            #pragma unroll
            for (int r = 0; r < 4; ++r) q[r] = f2bf(acc[mt][nt][r] + bias);
            if (tb + 3 < tend) {
                *(ushort4*)(orow + tb) = make_ushort4(q[0], q[1], q[2], q[3]);
            } else {
                for (int r = 0; r < 4 && tb + r < tend; ++r) orow[tb + r] = q[r];
            }
        }
    }
}

// ---------------------------------------------------------------------------
// K2: per block handles 4 consecutive b. Prefix sums (from K1 partials + the
// labeled tile's rows), snapshot x rows & running sums at the K labeled steps,
// then two 16x128x128 bf16 MFMA GEMMs: x2_lab = XL@w2^T, wms = MS@w3^T.
// Writes x2l[b][k][h] and c[b][k][h] = x2l + wms (fp32).
// grid = B/4 = 512, block = 256.
// ---------------------------------------------------------------------------
__global__ __launch_bounds__(256) void k2_label(
    const float* __restrict__ x, const int* __restrict__ lengths,
    const float* __restrict__ w2, const float* __restrict__ w3,
    const float* __restrict__ partial,
    float* __restrict__ cws, float* __restrict__ x2l)
{
    const int bq  = blockIdx.x * 4;
    const int tid = threadIdx.x;
    const int i    = tid & 127;
    const int half = tid >> 7;

    __shared__ __align__(16) unsigned short axl[16][136];  // rows m = sub*4+k
    __shared__ __align__(16) unsigned short ams[16][136];

    for (int rnd = 0; rnd < 2; ++rnd) {
        const int sub = half + rnd * 2;
        const int b   = bq + sub;
        const int L   = lengths[b];
        const int start = (L > 4) ? (L - 4) : 0;
        const int jt0   = start >> 6;
        float p = 0.f;
        for (int j = 0; j < jt0; ++j)
            p += partial[((size_t)b * NTILE + j) * I_DIM + i];
        float ps[4] = {0.f, 0.f, 0.f, 0.f};
        float xl[4] = {0.f, 0.f, 0.f, 0.f};
        for (int t = jt0 * 64; t < L; ++t) {
            const float v = x[((size_t)t * B_DIM + b) * I_DIM + i];
            p += v;
            if (t >= start) { const int k = t - start; ps[k] = p; xl[k] = v; }
        }
        #pragma unroll
        for (int k = 0; k < 4; ++k) {
            axl[sub * 4 + k][i] = f2bf(xl[k]);
            ams[sub * 4 + k][i] = f2bf(ps[k] / (float)(start + k + 1));
        }
    }
    __syncthreads();

    const int lane = tid & 63, wv = tid >> 6, l15 = lane & 15, quad = lane >> 4;
    #pragma unroll
    for (int nt = 0; nt < 2; ++nt) {
        const int n = wv * 32 + nt * 16 + l15;      // output h
        f32x4 c1 = (f32x4){0.f, 0.f, 0.f, 0.f};
        f32x4 c2 = (f32x4){0.f, 0.f, 0.f, 0.f};
        #pragma unroll
        for (int ks = 0; ks < 4; ++ks) {
            const int kc = ks * 32 + quad * 8;
            const bf16x8 a1 = *(const bf16x8*)&axl[l15][kc];
            const bf16x8 a2 = *(const bf16x8*)&ams[l15][kc];
            const float4 q0 = *(const float4*)(w2 + (size_t)n * I_DIM + kc);
            const float4 q1 = *(const float4*)(w2 + (size_t)n * I_DIM + kc + 4);
            const float4 r0 = *(const float4*)(w3 + (size_t)n * I_DIM + kc);
            const float4 r1 = *(const float4*)(w3 + (size_t)n * I_DIM + kc + 4);
            BF8 bw2, bw3;
            bw2.u2[0] = make_ushort4(f2bf(q0.x), f2bf(q0.y), f2bf(q0.z), f2bf(q0.w));
            bw2.u2[1] = make_ushort4(f2bf(q1.x), f2bf(q1.y), f2bf(q1.z), f2bf(q1.w));
            bw3.u2[0] = make_ushort4(f2bf(r0.x), f2bf(r0.y), f2bf(r0.z), f2bf(r0.w));
            bw3.u2[1] = make_ushort4(f2bf(r1.x), f2bf(r1.y), f2bf(r1.z), f2bf(r1.w));
            c1 = __builtin_amdgcn_mfma_f32_16x16x32_bf16(a1, bw2.v, c1, 0, 0, 0);
            c2 = __builtin_amdgcn_mfma_f32_16x16x32_bf16(a2, bw3.v, c2, 0, 0, 0);
        }
        // D row = quad*4 + r  ->  b = bq+quad, k = r
        #pragma unroll
        for (int r = 0; r < 4; ++r) {
            const size_t o = ((size_t)(bq + quad) * 4 + r) * H_DIM + n;
            x2l[o] = c1[r];
            cws[o] = c1[r] + c2[r];
        }
    }
}

// ---------------------------------------------------------------------------
// K3: attention per b. sigma(x1+c) = 1/(1 + E*Ek), E = exp(-x1) computed ONCE
// per (s,h), Ek[h][k] = exp(-c) precomputed. Phase E: lane<->s, loop h
// (coalesced 128B/wave loads of x1w[b][h][s-tile]); stage x1 tile + att in LDS.
// Phase ACC: lane<->h, loop s: hacc[k][h] += att[k][s]*x1[s][h].
// grid = B, block = 128 (2 waves), s-tile = 128.
// ---------------------------------------------------------------------------
__global__ __launch_bounds__(128) void k3_attn(
    const unsigned short* __restrict__ x1w, const int* __restrict__ lengths,
    const float* __restrict__ w0, const float* __restrict__ cws,
    const float* __restrict__ x2l, float* __restrict__ out)
{
    const int b   = blockIdx.x;
    const int tid = threadIdx.x;
    const int L   = lengths[b];
    const int start = (L > 4) ? (L - 4) : 0;
    const int nv    = (L < 4) ? L : 4;

    __shared__ __align__(16) unsigned short x1t[128][130]; // [h][s] pad->conflict-free col reads
    __shared__ __align__(16) float attk[128][4];           // [s][k], b128 broadcast reads
    __shared__ __align__(16) float ekt[128][4];            // [h][k]
    __shared__ float w0s[128];

    w0s[tid] = w0[tid];
    #pragma unroll
    for (int k = 0; k < 4; ++k)
        ekt[tid][k] = __builtin_amdgcn_exp2f(
            -1.44269504f * cws[((size_t)b * 4 + k) * H_DIM + tid]);
    __syncthreads();

    float hacc[4] = {0.f, 0.f, 0.f, 0.f};
    const unsigned short* xb = x1w + (size_t)b * H_DIM * T_DIM;

    for (int s0 = 0; s0 < L; s0 += 128) {
        const int  s    = s0 + tid;
        const bool sval = s < L;
        float att0 = 0.f, att1 = 0.f, att2 = 0.f, att3 = 0.f;
        #pragma unroll 4
        for (int h = 0; h < 128; ++h) {
            const unsigned short raw = sval ? xb[(size_t)h * T_DIM + s] : (unsigned short)0;
            x1t[h][tid] = raw;
            const float xv = bf2f(raw);
            const float E  = __builtin_amdgcn_exp2f(xv * -1.44269504f);
            const f32x4 ek = *(const f32x4*)&ekt[h][0];  // wave-broadcast
            const float wh = w0s[h];
            att0 += wh * __builtin_amdgcn_rcpf(1.f + E * ek[0]);
            att1 += wh * __builtin_amdgcn_rcpf(1.f + E * ek[1]);
            att2 += wh * __builtin_amdgcn_rcpf(1.f + E * ek[2]);
            att3 += wh * __builtin_amdgcn_rcpf(1.f + E * ek[3]);
        }
        // causal + label-valid mask (select, NaN-safe)
        attk[tid][0] = (0 < nv && s <= start + 0) ? att0 : 0.f;
        attk[tid][1] = (1 < nv && s <= start + 1) ? att1 : 0.f;
        attk[tid][2] = (2 < nv && s <= start + 2) ? att2 : 0.f;
        attk[tid][3] = (3 < nv && s <= start + 3) ? att3 : 0.f;
        __syncthreads();

        const int smax = (L - s0 < 128) ? (L - s0) : 128;
        for (int ss = 0; ss < smax; ++ss) {
            const f32x4 a4 = *(const f32x4*)&attk[ss][0]; // broadcast
            const float xv = bf2f(x1t[tid][ss]);
            hacc[0] += a4[0] * xv;
            hacc[1] += a4[1] * xv;
            hacc[2] += a4[2] * xv;
            hacc[3] += a4[3] * xv;
        }
        __syncthreads();
    }

    #pragma unroll
    for (int k = 0; k < 4; ++k) {
        const size_t o = ((size_t)b * 4 + k) * H_DIM + tid;
        out[o] = (k < nv) ? (hacc[k] + x2l[o]) : 0.f;
    }
}

// ---------------------------------------------------------------------------
extern "C" void kernel_launch(void* const* d_in, const int* in_sizes, int n_in,
                              void* d_out, int out_size, void* d_ws, size_t ws_size,
                              hipStream_t stream) {
    (void)in_sizes; (void)n_in; (void)out_size; (void)ws_size;
    const float* x       = (const float*)d_in[0];
    const int*   lengths = (const int*)d_in[1];
    // d_in[2] = label_len (==4, hard-coded)
    const float* w0 = (const float*)d_in[3];
    const float* w1 = (const float*)d_in[4];
    const float* b1 = (const float*)d_in[5];
    const float* w2 = (const float*)d_in[6];
    const float* w3 = (const float*)d_in[7];
    float* out = (float*)d_out;

    // workspace carve-up (needs ~112 MB)
    const size_t x1w_bytes  = (size_t)B_DIM * H_DIM * T_DIM * 2;        // 104857600
    const size_t part_bytes = (size_t)B_DIM * NTILE * I_DIM * 4;        // 4194304
    const size_t ckh_bytes  = (size_t)B_DIM * 4 * H_DIM * 4;            // 4194304
    unsigned short* x1w  = (unsigned short*)d_ws;
    float* partial = (float*)((char*)d_ws + x1w_bytes);
    float* cws     = (float*)((char*)d_ws + x1w_bytes + part_bytes);
    float* x2l     = (float*)((char*)d_ws + x1w_bytes + part_bytes + ckh_bytes);

    k1_gemm<<<dim3(NTILE, B_DIM), 256, 0, stream>>>(x, lengths, w1, b1, x1w, partial);
    k2_label<<<dim3(B_DIM / 4), 256, 0, stream>>>(x, lengths, w2, w3, partial, cws, x2l);
    k3_attn<<<dim3(B_DIM), 128, 0, stream>>>(x1w, lengths, w0, cws, x2l, out);
}

// Round 2
// 402.938 us; speedup vs baseline: 1.5144x; 1.5144x over previous
//
#include <hip/hip_runtime.h>
#include <stdint.h>

// T,B,I,H,K = 200,2048,128,128,4
#define T_DIM 200
#define B_DIM 2048
#define I_DIM 128
#define H_DIM 128
#define TS    16     // t-tile rows per MFMA pass
#define XST   201    // x1t row stride (odd dword-ish stride -> conflict-free col reads)

typedef float  f32x4  __attribute__((ext_vector_type(4)));
typedef __bf16 bf16x8 __attribute__((ext_vector_type(8)));

union BF8 { ushort4 u2[2]; bf16x8 v; };

static __device__ __forceinline__ unsigned short f2bf(float f) {
    union { float f; unsigned u; } c; c.f = f;
    unsigned u = c.u + (0x7FFFu + ((c.u >> 16) & 1u));   // RNE
    return (unsigned short)(u >> 16);
}
static __device__ __forceinline__ float bf2f(unsigned short s) {
    union { unsigned u; float f; } c; c.u = ((unsigned)s) << 16;
    return c.f;
}

// One block per batch element b. Everything stays in LDS:
//  1) tile loop: stage x[t0..t0+15][b][:] -> bf16 xs; colsum prefix (+label
//     capture via unrolled compare-select, no dynamic indexing); 16x128x128
//     MFMA -> x1t[h][t] bf16 (x1 = x@w1^T + b1)
//  2) mini-GEMM: {x_lab, m_s_lab} @ {w2,w3}^T via one 16x16x32 MFMA chain
//     (A rows duplicated l15&3; only quad0 rows 0..3 are real) -> x2ls, ekt=exp(-c)
//  3) E phase: att[k][s] = sum_h w0[h] / (1 + exp(-x1[s][h]) * ekt[h][k])
//     fully LDS-fed (one exp per (s,h), 4 rcp)
//  4) ACC: h[k][h] = sum_s att[k][s]*x1[s][h], split over thread halves,
//     combined through ekt's storage (dead after E), + x2_lab, masked store.
__global__ __launch_bounds__(256) void fused_kernel(
    const float* __restrict__ x, const int* __restrict__ lengths,
    const float* __restrict__ w0, const float* __restrict__ w1,
    const float* __restrict__ b1, const float* __restrict__ w2,
    const float* __restrict__ w3, float* __restrict__ out)
{
    __shared__ __align__(16) unsigned short xs[TS][136];     //  4352 B
    __shared__ __align__(16) unsigned short x1t[H_DIM][XST]; // 51456 B
    __shared__ __align__(16) unsigned short axl[4][136];     //  1088 B
    __shared__ __align__(16) unsigned short ams[4][136];     //  1088 B
    __shared__ __align__(16) float ekt[H_DIM][4];            //  2048 B (reused as hacc2)
    __shared__ __align__(16) float x2ls[4][H_DIM];           //  2048 B
    __shared__ __align__(16) float attk[XST][4];             //  3216 B
    // total 65296 B -> 2 blocks/CU

    const int b    = blockIdx.x;
    const int tid  = threadIdx.x;
    const int lane = tid & 63;
    const int wv   = tid >> 6;
    const int l15  = lane & 15;
    const int quad = lane >> 4;
    const int L     = lengths[b];
    const int start = (L > 4) ? (L - 4) : 0;
    const int nv    = (L < 4) ? L : 4;

    // ---- preload w1 B-frags (bf16) + bias; wave wv owns h in [32wv, 32wv+32) ----
    bf16x8 bfr[2][4];
    float  bias[2];
    #pragma unroll
    for (int nt = 0; nt < 2; ++nt) {
        const int n = wv * 32 + nt * 16 + l15;
        bias[nt] = b1[n];
        #pragma unroll
        for (int ks = 0; ks < 4; ++ks) {
            const int kc = ks * 32 + quad * 8;
            const float4 p0 = *(const float4*)(w1 + (size_t)n * I_DIM + kc);
            const float4 p1 = *(const float4*)(w1 + (size_t)n * I_DIM + kc + 4);
            BF8 t;
            t.u2[0] = make_ushort4(f2bf(p0.x), f2bf(p0.y), f2bf(p0.z), f2bf(p0.w));
            t.u2[1] = make_ushort4(f2bf(p1.x), f2bf(p1.y), f2bf(p1.z), f2bf(p1.w));
            bfr[nt][ks] = t.v;
        }
    }

    // prefix state (meaningful for tid<128; i = tid)
    float p = 0.f;
    float ps0 = 0.f, ps1 = 0.f, ps2 = 0.f, ps3 = 0.f;
    unsigned short xl0 = 0, xl1 = 0, xl2 = 0, xl3 = 0;

    // ---- tile loop: x1 GEMM + prefix sums ----
    for (int t0 = 0; t0 < L; t0 += TS) {
        const int nrows = (L - t0 < TS) ? (L - t0) : TS;
        #pragma unroll
        for (int it = 0; it < 2; ++it) {
            const int sl = tid + it * 256;          // TS*32 = 512 slots
            const int r = sl >> 5, f4 = sl & 31;
            if (r < nrows) {
                const float4 v = *(const float4*)(
                    x + ((size_t)(t0 + r) * B_DIM + b) * I_DIM + f4 * 4);
                *(ushort4*)(&xs[r][f4 * 4]) =
                    make_ushort4(f2bf(v.x), f2bf(v.y), f2bf(v.z), f2bf(v.w));
            }
        }
        __syncthreads();

        // colsum prefix + labeled-row capture (waves 0-1), concurrent with MFMA
        if (tid < 128) {
            const int s0 = start - t0;
            for (int r = 0; r < nrows; ++r) {
                const unsigned short raw = xs[r][tid];
                p += bf2f(raw);
                if (r == s0    ) { ps0 = p; xl0 = raw; }
                if (r == s0 + 1) { ps1 = p; xl1 = raw; }
                if (r == s0 + 2) { ps2 = p; xl2 = raw; }
                if (r == s0 + 3) { ps3 = p; xl3 = raw; }
            }
        }

        // 16-row MFMA: all waves
        bf16x8 afr[4];
        #pragma unroll
        for (int ks = 0; ks < 4; ++ks)
            afr[ks] = *(const bf16x8*)&xs[l15][ks * 32 + quad * 8];
        #pragma unroll
        for (int nt = 0; nt < 2; ++nt) {
            f32x4 acc = (f32x4){0.f, 0.f, 0.f, 0.f};
            #pragma unroll
            for (int ks = 0; ks < 4; ++ks)
                acc = __builtin_amdgcn_mfma_f32_16x16x32_bf16(afr[ks], bfr[nt][ks], acc, 0, 0, 0);
            const int h  = wv * 32 + nt * 16 + l15;
            const int tb = t0 + quad * 4;
            #pragma unroll
            for (int r = 0; r < 4; ++r) {
                const int t = tb + r;
                if (t - t0 < nrows) x1t[h][t] = f2bf(acc[r] + bias[nt]);
            }
        }
        __syncthreads();   // before next tile overwrites xs
    }

    // ---- labeled rows -> LDS (rows k>=nv stay zero; masked downstream) ----
    if (tid < 128) {
        axl[0][tid] = xl0; axl[1][tid] = xl1; axl[2][tid] = xl2; axl[3][tid] = xl3;
        ams[0][tid] = f2bf(ps0 / (float)(start + 1));
        ams[1][tid] = f2bf(ps1 / (float)(start + 2));
        ams[2][tid] = f2bf(ps2 / (float)(start + 3));
        ams[3][tid] = f2bf(ps3 / (float)(start + 4));
    }
    __syncthreads();

    // ---- mini-GEMM: x2_lab = XL@w2^T, wms = MS@w3^T; ekt = exp(-c) ----
    #pragma unroll
    for (int nt = 0; nt < 2; ++nt) {
        const int n = wv * 32 + nt * 16 + l15;
        f32x4 c1 = (f32x4){0.f, 0.f, 0.f, 0.f};
        f32x4 c2 = (f32x4){0.f, 0.f, 0.f, 0.f};
        #pragma unroll
        for (int ks = 0; ks < 4; ++ks) {
            const int kc = ks * 32 + quad * 8;
            const bf16x8 a1 = *(const bf16x8*)&axl[l15 & 3][kc];
            const bf16x8 a2 = *(const bf16x8*)&ams[l15 & 3][kc];
            const float4 q0 = *(const float4*)(w2 + (size_t)n * I_DIM + kc);
            const float4 q1 = *(const float4*)(w2 + (size_t)n * I_DIM + kc + 4);
            const float4 r0 = *(const float4*)(w3 + (size_t)n * I_DIM + kc);
            const float4 r1 = *(const float4*)(w3 + (size_t)n * I_DIM + kc + 4);
            BF8 bw2, bw3;
            bw2.u2[0] = make_ushort4(f2bf(q0.x), f2bf(q0.y), f2bf(q0.z), f2bf(q0.w));
            bw2.u2[1] = make_ushort4(f2bf(q1.x), f2bf(q1.y), f2bf(q1.z), f2bf(q1.w));
            bw3.u2[0] = make_ushort4(f2bf(r0.x), f2bf(r0.y), f2bf(r0.z), f2bf(r0.w));
            bw3.u2[1] = make_ushort4(f2bf(r1.x), f2bf(r1.y), f2bf(r1.z), f2bf(r1.w));
            c1 = __builtin_amdgcn_mfma_f32_16x16x32_bf16(a1, bw2.v, c1, 0, 0, 0);
            c2 = __builtin_amdgcn_mfma_f32_16x16x32_bf16(a2, bw3.v, c2, 0, 0, 0);
        }
        if (quad == 0) {          // D rows 0..3 = labeled k
            #pragma unroll
            for (int r = 0; r < 4; ++r) {
                x2ls[r][n] = c1[r];
                ekt[n][r]  = __builtin_amdgcn_exp2f(-1.44269504f * (c1[r] + c2[r]));
            }
        }
    }
    __syncthreads();

    // ---- E phase: att[k][s], fully LDS-fed ----
    const int s = tid;
    if (s < L) {
        float a0 = 0.f, a1 = 0.f, a2 = 0.f, a3 = 0.f;
        #pragma unroll 8
        for (int h = 0; h < H_DIM; ++h) {
            const float xv = bf2f(x1t[h][s]);                 // 2 lanes/bank: free
            const float E  = __builtin_amdgcn_exp2f(-1.44269504f * xv);
            const f32x4 ek = *(const f32x4*)&ekt[h][0];       // broadcast
            const float wh = w0[h];                            // uniform -> s_load, L1
            a0 += wh * __builtin_amdgcn_rcpf(1.f + E * ek[0]);
            a1 += wh * __builtin_amdgcn_rcpf(1.f + E * ek[1]);
            a2 += wh * __builtin_amdgcn_rcpf(1.f + E * ek[2]);
            a3 += wh * __builtin_amdgcn_rcpf(1.f + E * ek[3]);
        }
        attk[s][0] = (0 < nv && s <= start    ) ? a0 : 0.f;
        attk[s][1] = (1 < nv && s <= start + 1) ? a1 : 0.f;
        attk[s][2] = (2 < nv && s <= start + 2) ? a2 : 0.f;
        attk[s][3] = (3 < nv && s <= start + 3) ? a3 : 0.f;
    }
    __syncthreads();

    // ---- ACC: h[k][.] = sum_s att[k][s] * x1[s][.], split over halves ----
    const int h    = tid & 127;
    const int half = tid >> 7;
    const int Lh   = (L + 1) >> 1;
    const int ssb  = half ? Lh : 0;
    const int sse  = half ? L  : Lh;
    float h0 = 0.f, h1 = 0.f, h2 = 0.f, h3 = 0.f;
    #pragma unroll 4
    for (int ss = ssb; ss < sse; ++ss) {
        const f32x4 a4 = *(const f32x4*)&attk[ss][0];          // broadcast
        const float xv = bf2f(x1t[h][ss]);                     // stride 402B: ~2-way, free
        h0 += a4[0] * xv; h1 += a4[1] * xv; h2 += a4[2] * xv; h3 += a4[3] * xv;
    }
    float* hacc2 = (float*)&ekt[0][0];                         // ekt dead after E
    if (half) {
        hacc2[h * 4 + 0] = h0; hacc2[h * 4 + 1] = h1;
        hacc2[h * 4 + 2] = h2; hacc2[h * 4 + 3] = h3;
    }
    __syncthreads();
    if (tid < 128) {
        h0 += hacc2[h * 4 + 0]; h1 += hacc2[h * 4 + 1];
        h2 += hacc2[h * 4 + 2]; h3 += hacc2[h * 4 + 3];
        out[((size_t)b * 4 + 0) * H_DIM + h] = (0 < nv) ? h0 + x2ls[0][h] : 0.f;
        out[((size_t)b * 4 + 1) * H_DIM + h] = (1 < nv) ? h1 + x2ls[1][h] : 0.f;
        out[((size_t)b * 4 + 2) * H_DIM + h] = (2 < nv) ? h2 + x2ls[2][h] : 0.f;
        out[((size_t)b * 4 + 3) * H_DIM + h] = (3 < nv) ? h3 + x2ls[3][h] : 0.f;
    }
}

extern "C" void kernel_launch(void* const* d_in, const int* in_sizes, int n_in,
                              void* d_out, int out_size, void* d_ws, size_t ws_size,
                              hipStream_t stream) {
    (void)in_sizes; (void)n_in; (void)out_size; (void)d_ws; (void)ws_size;
    const float* x       = (const float*)d_in[0];
    const int*   lengths = (const int*)d_in[1];
    // d_in[2] = label_len (==4, hard-coded)
    const float* w0 = (const float*)d_in[3];
    const float* w1 = (const float*)d_in[4];
    const float* b1 = (const float*)d_in[5];
    const float* w2 = (const float*)d_in[6];
    const float* w3 = (const float*)d_in[7];
    float* out = (float*)d_out;

    fused_kernel<<<dim3(B_DIM), 256, 0, stream>>>(x, lengths, w0, w1, b1, w2, w3, out);
}

// Round 3
// 386.585 us; speedup vs baseline: 1.5785x; 1.0423x over previous
//
#include <hip/hip_runtime.h>
#include <stdint.h>

// T,B,I,H,K = 200,2048,128,128,4
#define T_DIM 200
#define B_DIM 2048
#define I_DIM 128
#define H_DIM 128
#define TS    32      // t rows per tile

typedef float  f32x4  __attribute__((ext_vector_type(4)));
typedef __bf16 bf16x8 __attribute__((ext_vector_type(8)));

union BF8 { ushort4 u2[2]; bf16x8 v; };

static __device__ __forceinline__ unsigned short f2bf(float f) {
    union { float f; unsigned u; } c; c.f = f;
    unsigned u = c.u + (0x7FFFu + ((c.u >> 16) & 1u));   // RNE
    return (unsigned short)(u >> 16);
}
static __device__ __forceinline__ float bf2f(unsigned short s) {
    union { unsigned u; float f; } c; c.u = ((unsigned)s) << 16;
    return c.f;
}

// One block per b; ~29 KB LDS -> 5 blocks/CU (20 waves) for latency hiding.
// Phases: A) strided-coalesced column prefix sums (t split across 2 halves),
// B) mini-GEMM -> ekt = exp(-(x2_lab + wms_lab)), x2ls, C) tile loop over t:
// stage->MFMA(x1)->E(att partials, 32s x 8 h-groups)->masked reduce->ACC.
// x1 never persists beyond a tile; all masks applied post-sum (garbage-safe).
__global__ __launch_bounds__(256, 4) void fused_kernel(
    const float* __restrict__ x, const int* __restrict__ lengths,
    const float* __restrict__ w0, const float* __restrict__ w1,
    const float* __restrict__ b1, const float* __restrict__ w2,
    const float* __restrict__ w3, float* __restrict__ out)
{
    __shared__ __align__(16) unsigned short xs[TS][136];   //  8704 B
    __shared__ __align__(16) unsigned short x1s[TS][130];  //  8320 B (65 dw stride: 2-way only)
    __shared__ __align__(16) float attp[TS][36];           //  4608 B (also psum / hacc2 reuse)
    __shared__ __align__(16) float attk[TS][4];            //   512 B
    __shared__ __align__(16) float ektL[H_DIM][4];         //  2048 B
    __shared__ __align__(16) float x2ls[4][H_DIM];         //  2048 B
    __shared__ __align__(16) float w0s[H_DIM];             //   512 B
    __shared__ __align__(16) unsigned short axl[4][136];   //  1088 B
    __shared__ __align__(16) unsigned short ams[4][136];   //  1088 B
    // total ~28.9 KB

    const int b    = blockIdx.x;
    const int tid  = threadIdx.x;
    const int lane = tid & 63;
    const int wv   = tid >> 6;
    const int l15  = lane & 15;
    const int quad = lane >> 4;
    const int L     = lengths[b];
    const int start = (L > 4) ? (L - 4) : 0;
    const int nv    = (L < 4) ? L : 4;

    if (tid < 128) w0s[tid] = w0[tid];

    // ---- preload w1 B-frags + bias (regs; independent of everything) ----
    bf16x8 bfr[2][4];
    float  bias[2];
    #pragma unroll
    for (int nt = 0; nt < 2; ++nt) {
        const int n = wv * 32 + nt * 16 + l15;
        bias[nt] = b1[n];
        #pragma unroll
        for (int ks = 0; ks < 4; ++ks) {
            const int kc = ks * 32 + quad * 8;
            const float4 p0 = *(const float4*)(w1 + (size_t)n * I_DIM + kc);
            const float4 p1 = *(const float4*)(w1 + (size_t)n * I_DIM + kc + 4);
            BF8 t;
            t.u2[0] = make_ushort4(f2bf(p0.x), f2bf(p0.y), f2bf(p0.z), f2bf(p0.w));
            t.u2[1] = make_ushort4(f2bf(p1.x), f2bf(p1.y), f2bf(p1.z), f2bf(p1.w));
            bfr[nt][ks] = t.v;
        }
    }

    // ---- A: column prefix sums over t in [0,start), split across halves ----
    const int i    = tid & 127;
    const int half = tid >> 7;
    const int m    = start >> 1;
    const float* xp = x + (size_t)b * I_DIM + i;   // + t*B*I walks time
    {
        const int tb = half ? m : 0;
        const int te = half ? start : m;
        float s = 0.f;
        int t = tb;
        for (; t + 4 <= te; t += 4) {   // 4 independent strided loads in flight
            const float a0 = xp[(size_t)(t + 0) * (B_DIM * I_DIM)];
            const float a1 = xp[(size_t)(t + 1) * (B_DIM * I_DIM)];
            const float a2 = xp[(size_t)(t + 2) * (B_DIM * I_DIM)];
            const float a3 = xp[(size_t)(t + 3) * (B_DIM * I_DIM)];
            s += a0 + a1 + a2 + a3;
        }
        for (; t < te; ++t) s += xp[(size_t)t * (B_DIM * I_DIM)];
        float* psum = &attp[0][0];      // attp reused as [2][128] partial sums
        psum[half * 128 + i] = s;
    }
    __syncthreads();

    if (tid < 128) {
        float* psum = &attp[0][0];
        float p = psum[i] + psum[128 + i];
        // labeled rows t = start..start+3 (always < T; k>=nv garbage is masked later)
        const float v0 = xp[(size_t)(start + 0) * (B_DIM * I_DIM)];
        const float v1 = xp[(size_t)(start + 1) * (B_DIM * I_DIM)];
        const float v2 = xp[(size_t)(start + 2) * (B_DIM * I_DIM)];
        const float v3 = xp[(size_t)(start + 3) * (B_DIM * I_DIM)];
        const float p0 = p + v0, p1 = p0 + v1, p2 = p1 + v2, p3 = p2 + v3;
        axl[0][i] = f2bf(v0); axl[1][i] = f2bf(v1);
        axl[2][i] = f2bf(v2); axl[3][i] = f2bf(v3);
        ams[0][i] = f2bf(p0 / (float)(start + 1));
        ams[1][i] = f2bf(p1 / (float)(start + 2));
        ams[2][i] = f2bf(p2 / (float)(start + 3));
        ams[3][i] = f2bf(p3 / (float)(start + 4));
    }
    __syncthreads();

    // ---- B: mini-GEMM {x_lab, m_s}@{w2,w3}^T -> ektL=exp(-c), x2ls ----
    #pragma unroll
    for (int nt = 0; nt < 2; ++nt) {
        const int n = wv * 32 + nt * 16 + l15;
        f32x4 c1 = (f32x4){0.f, 0.f, 0.f, 0.f};
        f32x4 c2 = (f32x4){0.f, 0.f, 0.f, 0.f};
        #pragma unroll
        for (int ks = 0; ks < 4; ++ks) {
            const int kc = ks * 32 + quad * 8;
            const bf16x8 a1 = *(const bf16x8*)&axl[l15 & 3][kc];
            const bf16x8 a2 = *(const bf16x8*)&ams[l15 & 3][kc];
            const float4 q0 = *(const float4*)(w2 + (size_t)n * I_DIM + kc);
            const float4 q1 = *(const float4*)(w2 + (size_t)n * I_DIM + kc + 4);
            const float4 r0 = *(const float4*)(w3 + (size_t)n * I_DIM + kc);
            const float4 r1 = *(const float4*)(w3 + (size_t)n * I_DIM + kc + 4);
            BF8 bw2, bw3;
            bw2.u2[0] = make_ushort4(f2bf(q0.x), f2bf(q0.y), f2bf(q0.z), f2bf(q0.w));
            bw2.u2[1] = make_ushort4(f2bf(q1.x), f2bf(q1.y), f2bf(q1.z), f2bf(q1.w));
            bw3.u2[0] = make_ushort4(f2bf(r0.x), f2bf(r0.y), f2bf(r0.z), f2bf(r0.w));
            bw3.u2[1] = make_ushort4(f2bf(r1.x), f2bf(r1.y), f2bf(r1.z), f2bf(r1.w));
            c1 = __builtin_amdgcn_mfma_f32_16x16x32_bf16(a1, bw2.v, c1, 0, 0, 0);
            c2 = __builtin_amdgcn_mfma_f32_16x16x32_bf16(a2, bw3.v, c2, 0, 0, 0);
        }
        if (quad == 0) {    // D rows 0..3 = labeled k
            #pragma unroll
            for (int r = 0; r < 4; ++r) {
                x2ls[r][n] = c1[r];
                ektL[n][r] = __builtin_amdgcn_exp2f(-1.44269504f * (c1[r] + c2[r]));
            }
        }
    }
    __syncthreads();

    // ---- C: tile loop ----
    const int sq = tid & 31;          // E-phase s within tile
    const int hg = tid >> 5;          // E-phase h-group (8 groups x 16 h)
    const int hcol = tid & 127;       // ACC h
    float hacc0 = 0.f, hacc1 = 0.f, hacc2v = 0.f, hacc3 = 0.f;

    for (int t0 = 0; t0 < L; t0 += TS) {
        const int nrows = (L - t0 < TS) ? (L - t0) : TS;

        // stage (zero-fill invalid rows -> everything downstream finite)
        #pragma unroll
        for (int it = 0; it < 4; ++it) {
            const int sl = tid + it * 256;          // TS*32 = 1024 slots
            const int r = sl >> 5, f4 = sl & 31;
            ushort4 w = make_ushort4(0, 0, 0, 0);
            if (r < nrows) {
                const float4 v = *(const float4*)(
                    x + ((size_t)(t0 + r) * B_DIM + b) * I_DIM + f4 * 4);
                w = make_ushort4(f2bf(v.x), f2bf(v.y), f2bf(v.z), f2bf(v.w));
            }
            *(ushort4*)&xs[r][f4 * 4] = w;
        }
        __syncthreads();

        // MFMA: x1 tile (32 t x 128 h), write [t][h] bf16
        #pragma unroll
        for (int mt = 0; mt < 2; ++mt) {
            bf16x8 afr[4];
            #pragma unroll
            for (int ks = 0; ks < 4; ++ks)
                afr[ks] = *(const bf16x8*)&xs[mt * 16 + l15][ks * 32 + quad * 8];
            #pragma unroll
            for (int nt = 0; nt < 2; ++nt) {
                f32x4 acc = (f32x4){0.f, 0.f, 0.f, 0.f};
                #pragma unroll
                for (int ks = 0; ks < 4; ++ks)
                    acc = __builtin_amdgcn_mfma_f32_16x16x32_bf16(
                        afr[ks], bfr[nt][ks], acc, 0, 0, 0);
                const int h = wv * 32 + nt * 16 + l15;
                const int tr = mt * 16 + quad * 4;
                #pragma unroll
                for (int r = 0; r < 4; ++r)
                    x1s[tr + r][h] = f2bf(acc[r] + bias[nt]);
            }
        }
        __syncthreads();

        // E: att partials; thread (sq, hg) covers 16 h; one exp + 4 rcp per h
        {
            const int h0 = hg * 16;
            f32x4 a = (f32x4){0.f, 0.f, 0.f, 0.f};
            #pragma unroll
            for (int hh = 0; hh < 16; hh += 2) {
                const int h = h0 + hh;
                const unsigned xv2 = *(const unsigned*)&x1s[sq][h];
                const float xa = bf2f((unsigned short)(xv2 & 0xFFFFu));
                const float xb = bf2f((unsigned short)(xv2 >> 16));
                const float Ea = __builtin_amdgcn_exp2f(-1.44269504f * xa);
                const float Eb = __builtin_amdgcn_exp2f(-1.44269504f * xb);
                const f32x4 eka = *(const f32x4*)&ektL[h][0];
                const f32x4 ekb = *(const f32x4*)&ektL[h + 1][0];
                const float wa = w0s[h], wb = w0s[h + 1];
                #pragma unroll
                for (int k = 0; k < 4; ++k)
                    a[k] += wa * __builtin_amdgcn_rcpf(1.f + Ea * eka[k])
                          + wb * __builtin_amdgcn_rcpf(1.f + Eb * ekb[k]);
            }
            *(f32x4*)&attp[sq][hg * 4] = a;
        }
        __syncthreads();

        // reduce 8 h-group partials + mask (NaN/garbage-safe: select after sum)
        if (tid < TS) {
            const int s = t0 + tid;
            f32x4 sm = (f32x4){0.f, 0.f, 0.f, 0.f};
            #pragma unroll
            for (int g = 0; g < 8; ++g)
                sm += *(const f32x4*)&attp[tid][g * 4];
            f32x4 o;
            o[0] = (0 < nv && s <= start    ) ? sm[0] : 0.f;
            o[1] = (1 < nv && s <= start + 1) ? sm[1] : 0.f;
            o[2] = (2 < nv && s <= start + 2) ? sm[2] : 0.f;
            o[3] = (3 < nv && s <= start + 3) ? sm[3] : 0.f;
            *(f32x4*)&attk[tid][0] = o;
        }
        __syncthreads();

        // ACC: hacc[k][h] += sum_s att[k][s]*x1[s][h]; halves split the 16+16 rows
        {
            const int sbase = half * 16;
            #pragma unroll
            for (int s2 = 0; s2 < 16; ++s2) {
                const int srow = sbase + s2;
                const f32x4 a4 = *(const f32x4*)&attk[srow][0];   // broadcast
                const float xv = bf2f(x1s[srow][hcol]);           // row-broadcast, 2-way
                hacc0 += a4[0] * xv; hacc1 += a4[1] * xv;
                hacc2v += a4[2] * xv; hacc3 += a4[3] * xv;
            }
        }
        __syncthreads();
    }

    // ---- epilogue: combine halves via LDS (attp reuse), +x2_lab, mask, store ----
    {
        float* h2 = &attp[0][0];    // [128][4]
        if (half == 1) {
            *(f32x4*)&h2[hcol * 4] = (f32x4){hacc0, hacc1, hacc2v, hacc3};
        }
        __syncthreads();
        if (tid < 128) {
            const f32x4 o = *(const f32x4*)&h2[hcol * 4];
            hacc0 += o[0]; hacc1 += o[1]; hacc2v += o[2]; hacc3 += o[3];
            out[((size_t)b * 4 + 0) * H_DIM + hcol] = (0 < nv) ? hacc0 + x2ls[0][hcol] : 0.f;
            out[((size_t)b * 4 + 1) * H_DIM + hcol] = (1 < nv) ? hacc1 + x2ls[1][hcol] : 0.f;
            out[((size_t)b * 4 + 2) * H_DIM + hcol] = (2 < nv) ? hacc2v + x2ls[2][hcol] : 0.f;
            out[((size_t)b * 4 + 3) * H_DIM + hcol] = (3 < nv) ? hacc3 + x2ls[3][hcol] : 0.f;
        }
    }
}

extern "C" void kernel_launch(void* const* d_in, const int* in_sizes, int n_in,
                              void* d_out, int out_size, void* d_ws, size_t ws_size,
                              hipStream_t stream) {
    (void)in_sizes; (void)n_in; (void)out_size; (void)d_ws; (void)ws_size;
    const float* x       = (const float*)d_in[0];
    const int*   lengths = (const int*)d_in[1];
    // d_in[2] = label_len (==4, hard-coded)
    const float* w0 = (const float*)d_in[3];
    const float* w1 = (const float*)d_in[4];
    const float* b1 = (const float*)d_in[5];
    const float* w2 = (const float*)d_in[6];
    const float* w3 = (const float*)d_in[7];
    float* out = (float*)d_out;

    fused_kernel<<<dim3(B_DIM), 256, 0, stream>>>(x, lengths, w0, w1, b1, w2, w3, out);
}